// Round 1
// baseline (470.581 us; speedup 1.0000x reference)
//
#include <hip/hip_runtime.h>

// Causal depthwise conv1d, fp32.
// out[b,t,c] = bias[c] + sum_{k=0..3} x[b, t-3+k, c] * weight[c*K + k]
// x: [B,T,C] (C innermost), weight: [C,1,K], bias: [C].
// Memory-bound streaming kernel: each thread owns 4 consecutive channels
// (float4) and slides a 3-deep register window across a 64-long t-chunk.

constexpr int B = 8;
constexpr int T = 4096;
constexpr int C = 2048;
constexpr int K = 4;
constexpr int TCHUNK = 64;              // t-steps per block
constexpr int THREADS = C / 4;          // 512: one float4 channel-group per thread

__global__ __launch_bounds__(THREADS) void dwconv_causal_kernel(
    const float* __restrict__ x,
    const float* __restrict__ w,      // [C,1,K] flat: w[c*K + k]
    const float* __restrict__ bias,   // [C]
    float* __restrict__ out)
{
    const int c = threadIdx.x * 4;                 // first of 4 channels
    const int chunk = blockIdx.x;                  // 0 .. B*(T/TCHUNK)-1
    const int b  = chunk / (T / TCHUNK);
    const int t0 = (chunk % (T / TCHUNK)) * TCHUNK;

    // Per-channel tap weights: wk[k].{x,y,z,w} = w[(c+j)*K + k]
    float4 wk[K];
#pragma unroll
    for (int k = 0; k < K; ++k) {
        wk[k].x = w[(c + 0) * K + k];
        wk[k].y = w[(c + 1) * K + k];
        wk[k].z = w[(c + 2) * K + k];
        wk[k].w = w[(c + 3) * K + k];
    }
    const float4 bv = *reinterpret_cast<const float4*>(bias + c);

    const float* xb = x   + (size_t)b * T * C;
    float*       ob = out + (size_t)b * T * C;

    // Sliding window registers: x[t-3], x[t-2], x[t-1]
    float4 xm3, xm2, xm1;
    if (t0 == 0) {
        xm3 = make_float4(0.f, 0.f, 0.f, 0.f);
        xm2 = xm3;
        xm1 = xm3;
    } else {
        xm3 = *reinterpret_cast<const float4*>(xb + (size_t)(t0 - 3) * C + c);
        xm2 = *reinterpret_cast<const float4*>(xb + (size_t)(t0 - 2) * C + c);
        xm1 = *reinterpret_cast<const float4*>(xb + (size_t)(t0 - 1) * C + c);
    }

#pragma unroll 4
    for (int t = t0; t < t0 + TCHUNK; ++t) {
        const float4 cur = *reinterpret_cast<const float4*>(xb + (size_t)t * C + c);
        float4 o;
        o.x = bv.x + wk[0].x * xm3.x + wk[1].x * xm2.x + wk[2].x * xm1.x + wk[3].x * cur.x;
        o.y = bv.y + wk[0].y * xm3.y + wk[1].y * xm2.y + wk[2].y * xm1.y + wk[3].y * cur.y;
        o.z = bv.z + wk[0].z * xm3.z + wk[1].z * xm2.z + wk[2].z * xm1.z + wk[3].z * cur.z;
        o.w = bv.w + wk[0].w * xm3.w + wk[1].w * xm2.w + wk[2].w * xm1.w + wk[3].w * cur.w;
        *reinterpret_cast<float4*>(ob + (size_t)t * C + c) = o;
        xm3 = xm2; xm2 = xm1; xm1 = cur;
    }
}

extern "C" void kernel_launch(void* const* d_in, const int* in_sizes, int n_in,
                              void* d_out, int out_size, void* d_ws, size_t ws_size,
                              hipStream_t stream) {
    const float* x    = (const float*)d_in[0];
    const float* w    = (const float*)d_in[1];
    const float* bias = (const float*)d_in[2];
    float* out = (float*)d_out;

    const int grid = B * (T / TCHUNK);   // 512 blocks
    dwconv_causal_kernel<<<grid, THREADS, 0, stream>>>(x, w, bias, out);
}